// Round 1
// baseline (1112.737 us; speedup 1.0000x reference)
//
#include <hip/hip_runtime.h>
#include <math.h>

#define N_ATOMS 20000
#define G_GRAPHS 500
#define DEG 16
#define E_EDGES (N_ATOMS * DEG)
#define HID 128
#define NF 128
#define TBL 8192
#define CUTOFF 10.0f
#define LOG2F_ 0.6931471805599453f

__device__ __forceinline__ float ssp_f(float x) {
  // softplus(x) - log(2), numerically stable
  float ax = fabsf(x);
  return fmaxf(x, 0.0f) + log1pf(expf(-ax)) - LOG2F_;
}

// ---------------- distances ----------------
__global__ void k_dist(const float* __restrict__ pos, const int* __restrict__ ei,
                       float* __restrict__ dist) {
  int e = blockIdx.x * blockDim.x + threadIdx.x;
  if (e >= E_EDGES) return;
  int r = ei[e], c = ei[E_EDGES + e];
  float dx = pos[3 * r + 0] - pos[3 * c + 0];
  float dy = pos[3 * r + 1] - pos[3 * c + 1];
  float dz = pos[3 * r + 2] - pos[3 * c + 2];
  dist[e] = sqrtf(dx * dx + dy * dy + dz * dz);
}

// ---------------- embedding gather ----------------
__global__ void k_embed(const float* __restrict__ emb, const int* __restrict__ z,
                        float* __restrict__ h) {
  int t = blockIdx.x * blockDim.x + threadIdx.x;
  if (t >= N_ATOMS * HID) return;
  int i = t >> 7, c = t & 127;
  h[t] = emb[z[i] * HID + c];
}

// ---------------- per-layer filter table: f_l(d) = (ssp(gauss(d)@W1+b1)@W2+b2)*C(d) ----------------
__global__ void k_table(const float* __restrict__ w1, const float* __restrict__ b1,
                        const float* __restrict__ w2, const float* __restrict__ b2,
                        float* __restrict__ table) {
  __shared__ float ea[NF];
  __shared__ float hidv[NF];
  int r = blockIdx.x;
  int j = threadIdx.x;  // 0..127
  float d = (CUTOFF / (float)(TBL - 1)) * (float)r;
  const float delta = CUTOFF / (float)(NF - 1);
  const float coeff = -0.5f / (delta * delta);
  float t = d - delta * (float)j;
  ea[j] = expf(coeff * t * t);
  __syncthreads();
  float acc = b1[j];
  for (int k = 0; k < NF; ++k) acc = fmaf(ea[k], w1[k * NF + j], acc);
  hidv[j] = ssp_f(acc);
  __syncthreads();
  float acc2 = b2[j];
  for (int k = 0; k < NF; ++k) acc2 = fmaf(hidv[k], w2[k * NF + j], acc2);
  float C = 0.5f * (cosf(d * (float)M_PI / CUTOFF) + 1.0f);
  table[r * NF + j] = acc2 * C;
}

// ---------------- x1 = h @ cf_w1 (4 nodes per block, 128 threads) ----------------
__global__ void k_x1(const float* __restrict__ h, const float* __restrict__ w,
                     float* __restrict__ x1) {
  __shared__ float hs[4][HID];
  int i0 = blockIdx.x * 4;
  int j = threadIdx.x;
#pragma unroll
  for (int m = 0; m < 4; ++m) hs[m][j] = h[(i0 + m) * HID + j];
  __syncthreads();
  float a0 = 0.f, a1 = 0.f, a2 = 0.f, a3 = 0.f;
  for (int k = 0; k < HID; ++k) {
    float wv = w[k * NF + j];
    a0 = fmaf(hs[0][k], wv, a0);
    a1 = fmaf(hs[1][k], wv, a1);
    a2 = fmaf(hs[2][k], wv, a2);
    a3 = fmaf(hs[3][k], wv, a3);
  }
  x1[(i0 + 0) * NF + j] = a0;
  x1[(i0 + 1) * NF + j] = a1;
  x1[(i0 + 2) * NF + j] = a2;
  x1[(i0 + 3) * NF + j] = a3;
}

// ---------------- per-edge: lerp table -> Wf, msg = x1[row]*Wf, atomic agg[col] ----------------
__global__ void k_edge(const float* __restrict__ dist, const int* __restrict__ ei,
                       const float* __restrict__ table, const float* __restrict__ x1,
                       float* __restrict__ agg) {
  int t = blockIdx.x * blockDim.x + threadIdx.x;
  int e = t >> 6;
  if (e >= E_EDGES) return;
  int lane = t & 63;
  int row = ei[e], col = ei[E_EDGES + e];
  float d = dist[e];
  float ft = d * ((float)(TBL - 1) / CUTOFF);
  int i0 = (int)ft;
  i0 = min(i0, TBL - 2);
  float fr = ft - (float)i0;
  const float2* t0 = (const float2*)(table + (size_t)i0 * NF);
  const float2* t1 = (const float2*)(table + (size_t)(i0 + 1) * NF);
  float2 a = t0[lane];
  float2 b = t1[lane];
  float2 xv = ((const float2*)(x1 + (size_t)row * NF))[lane];
  float w0 = fmaf(fr, b.x - a.x, a.x);
  float w1 = fmaf(fr, b.y - a.y, a.y);
  atomicAdd(&agg[(size_t)col * NF + lane * 2 + 0], xv.x * w0);
  atomicAdd(&agg[(size_t)col * NF + lane * 2 + 1], xv.y * w1);
}

// ---------------- node update: h += (ssp(agg@cf_w2+b2)) @ lin_w + lin_b ----------------
__global__ void k_update(const float* __restrict__ agg, const float* __restrict__ w2,
                         const float* __restrict__ b2, const float* __restrict__ lw,
                         const float* __restrict__ lb, float* __restrict__ h) {
  __shared__ float s[4][NF];
  __shared__ float u[4][NF];
  int i0 = blockIdx.x * 4;
  int j = threadIdx.x;
#pragma unroll
  for (int m = 0; m < 4; ++m) s[m][j] = agg[(i0 + m) * NF + j];
  __syncthreads();
  float bj = b2[j];
  float a0 = bj, a1 = bj, a2 = bj, a3 = bj;
  for (int k = 0; k < NF; ++k) {
    float wv = w2[k * HID + j];
    a0 = fmaf(s[0][k], wv, a0);
    a1 = fmaf(s[1][k], wv, a1);
    a2 = fmaf(s[2][k], wv, a2);
    a3 = fmaf(s[3][k], wv, a3);
  }
  u[0][j] = ssp_f(a0);
  u[1][j] = ssp_f(a1);
  u[2][j] = ssp_f(a2);
  u[3][j] = ssp_f(a3);
  __syncthreads();
  float lbj = lb[j];
  a0 = lbj; a1 = lbj; a2 = lbj; a3 = lbj;
  for (int k = 0; k < HID; ++k) {
    float wv = lw[k * HID + j];
    a0 = fmaf(u[0][k], wv, a0);
    a1 = fmaf(u[1][k], wv, a1);
    a2 = fmaf(u[2][k], wv, a2);
    a3 = fmaf(u[3][k], wv, a3);
  }
  h[(i0 + 0) * HID + j] += a0;
  h[(i0 + 1) * HID + j] += a1;
  h[(i0 + 2) * HID + j] += a2;
  h[(i0 + 3) * HID + j] += a3;
}

// ---------------- head: y = ssp(h@hw1+hb1)@hw2+hb2; out[g] += y ----------------
__global__ void k_head(const float* __restrict__ h, const float* __restrict__ hw1,
                       const float* __restrict__ hb1, const float* __restrict__ hw2,
                       const float* __restrict__ hb2, const int* __restrict__ batch,
                       float* __restrict__ out) {
  __shared__ float hs[4][HID];
  int i0 = blockIdx.x * 4;
  int j = threadIdx.x;  // 0..63
  for (int idx = j; idx < 4 * HID; idx += 64) hs[idx >> 7][idx & 127] = h[i0 * HID + idx];
  __syncthreads();
  float bj = hb1[j];
  float acc[4];
#pragma unroll
  for (int m = 0; m < 4; ++m) acc[m] = bj;
  for (int k = 0; k < HID; ++k) {
    float wv = hw1[k * 64 + j];
#pragma unroll
    for (int m = 0; m < 4; ++m) acc[m] = fmaf(hs[m][k], wv, acc[m]);
  }
  float w2v = hw2[j];
  float b2v = hb2[0];
  float ysum = 0.f;  // NPG=40 is divisible by 4 -> all 4 nodes in same graph
#pragma unroll
  for (int m = 0; m < 4; ++m) {
    float p = ssp_f(acc[m]) * w2v;
    for (int off = 32; off > 0; off >>= 1) p += __shfl_down(p, off);
    if (j == 0) ysum += p + b2v;
  }
  if (j == 0) atomicAdd(&out[batch[i0]], ysum);
}

extern "C" void kernel_launch(void* const* d_in, const int* in_sizes, int n_in,
                              void* d_out, int out_size, void* d_ws, size_t ws_size,
                              hipStream_t stream) {
  const float* pos    = (const float*)d_in[0];
  const float* emb    = (const float*)d_in[1];
  const float* mlp_w1 = (const float*)d_in[2];
  const float* mlp_b1 = (const float*)d_in[3];
  const float* mlp_w2 = (const float*)d_in[4];
  const float* mlp_b2 = (const float*)d_in[5];
  const float* cf_w1  = (const float*)d_in[6];
  const float* cf_w2  = (const float*)d_in[7];
  const float* cf_b2  = (const float*)d_in[8];
  const float* lin_w  = (const float*)d_in[9];
  const float* lin_b  = (const float*)d_in[10];
  const float* hw1    = (const float*)d_in[11];
  const float* hb1    = (const float*)d_in[12];
  const float* hw2    = (const float*)d_in[13];
  const float* hb2    = (const float*)d_in[14];
  const int*   z      = (const int*)d_in[15];
  const int*   batch  = (const int*)d_in[16];
  const int*   ei     = (const int*)d_in[17];

  float* ws  = (float*)d_ws;
  float* dist = ws;                          // E
  float* h    = dist + E_EDGES;              // N*HID
  float* x1   = h + (size_t)N_ATOMS * HID;   // N*NF
  float* agg  = x1 + (size_t)N_ATOMS * NF;   // N*NF
  float* tbl  = agg + (size_t)N_ATOMS * NF;  // 3*TBL*NF
  size_t need = ((size_t)E_EDGES + 3ull * N_ATOMS * HID + 3ull * TBL * NF) * 4ull;
  if (ws_size < need) return;  // fail loudly (wrong output) rather than corrupt

  k_dist<<<(E_EDGES + 255) / 256, 256, 0, stream>>>(pos, ei, dist);
  k_embed<<<(N_ATOMS * HID + 255) / 256, 256, 0, stream>>>(emb, z, h);
  for (int l = 0; l < 3; ++l) {
    k_table<<<TBL, NF, 0, stream>>>(mlp_w1 + (size_t)l * NF * NF, mlp_b1 + (size_t)l * NF,
                                    mlp_w2 + (size_t)l * NF * NF, mlp_b2 + (size_t)l * NF,
                                    tbl + (size_t)l * TBL * NF);
  }
  for (int l = 0; l < 3; ++l) {
    k_x1<<<N_ATOMS / 4, 128, 0, stream>>>(h, cf_w1 + (size_t)l * HID * NF, x1);
    hipMemsetAsync(agg, 0, (size_t)N_ATOMS * NF * 4, stream);
    k_edge<<<(E_EDGES * 64) / 256, 256, 0, stream>>>(dist, ei, tbl + (size_t)l * TBL * NF, x1, agg);
    k_update<<<N_ATOMS / 4, 128, 0, stream>>>(agg, cf_w2 + (size_t)l * NF * HID,
                                              cf_b2 + (size_t)l * HID,
                                              lin_w + (size_t)l * HID * HID,
                                              lin_b + (size_t)l * HID, h);
  }
  hipMemsetAsync(d_out, 0, G_GRAPHS * 4, stream);
  k_head<<<N_ATOMS / 4, 64, 0, stream>>>(h, hw1, hb1, hw2, hb2, batch, (float*)d_out);
}

// Round 2
// 940.143 us; speedup vs baseline: 1.1836x; 1.1836x over previous
//
#include <hip/hip_runtime.h>
#include <math.h>

#define N_ATOMS 20000
#define G_GRAPHS 500
#define NPG 40
#define DEG 16
#define E_EDGES (N_ATOMS * DEG)
#define EPM (NPG * DEG)          // 640 edges per molecule
#define HID 128
#define NF 128
#define TBL 8192
#define CUTOFF 10.0f
#define LOG2F_ 0.6931471805599453f

__device__ __forceinline__ float ssp_f(float x) {
  float ax = fabsf(x);
  return fmaxf(x, 0.0f) + log1pf(expf(-ax)) - LOG2F_;
}

// ---------------- distances ----------------
__global__ void k_dist(const float* __restrict__ pos, const int* __restrict__ ei,
                       float* __restrict__ dist) {
  int e = blockIdx.x * blockDim.x + threadIdx.x;
  if (e >= E_EDGES) return;
  int r = ei[e], c = ei[E_EDGES + e];
  float dx = pos[3 * r + 0] - pos[3 * c + 0];
  float dy = pos[3 * r + 1] - pos[3 * c + 1];
  float dz = pos[3 * r + 2] - pos[3 * c + 2];
  dist[e] = sqrtf(dx * dx + dy * dy + dz * dz);
}

// ---------------- embedding gather ----------------
__global__ void k_embed(const float* __restrict__ emb, const int* __restrict__ z,
                        float* __restrict__ h) {
  int t = blockIdx.x * blockDim.x + threadIdx.x;
  if (t >= N_ATOMS * HID) return;
  int i = t >> 7, c = t & 127;
  h[t] = emb[z[i] * HID + c];
}

// ---------------- filter table, 16 rows per block (weight reads amortized) ----------------
__global__ void k_table(const float* __restrict__ w1, const float* __restrict__ b1,
                        const float* __restrict__ w2, const float* __restrict__ b2,
                        float* __restrict__ table) {
  __shared__ float ea[16][NF];
  __shared__ float hidv[16][NF];
  int j = threadIdx.x;
  int rbase = blockIdx.x * 16;
  const float step = CUTOFF / (float)(TBL - 1);
  const float delta = CUTOFF / (float)(NF - 1);
  const float coeff = -0.5f / (delta * delta);
#pragma unroll
  for (int rr = 0; rr < 16; ++rr) {
    float d = step * (float)(rbase + rr);
    float t = d - delta * (float)j;
    ea[rr][j] = expf(coeff * t * t);
  }
  __syncthreads();
  float b1j = b1[j];
  float acc[16];
#pragma unroll
  for (int rr = 0; rr < 16; ++rr) acc[rr] = b1j;
  for (int k = 0; k < NF; ++k) {
    float wv = w1[k * NF + j];
#pragma unroll
    for (int rr = 0; rr < 16; ++rr) acc[rr] = fmaf(ea[rr][k], wv, acc[rr]);
  }
#pragma unroll
  for (int rr = 0; rr < 16; ++rr) hidv[rr][j] = ssp_f(acc[rr]);
  __syncthreads();
  float b2j = b2[j];
#pragma unroll
  for (int rr = 0; rr < 16; ++rr) acc[rr] = b2j;
  for (int k = 0; k < NF; ++k) {
    float wv = w2[k * NF + j];
#pragma unroll
    for (int rr = 0; rr < 16; ++rr) acc[rr] = fmaf(hidv[rr][k], wv, acc[rr]);
  }
#pragma unroll
  for (int rr = 0; rr < 16; ++rr) {
    float d = step * (float)(rbase + rr);
    float C = 0.5f * (cosf(d * (float)M_PI / CUTOFF) + 1.0f);
    table[(size_t)(rbase + rr) * NF + j] = acc[rr] * C;
  }
}

// ---------------- x1 = h @ cf_w1 (4 nodes per block) ----------------
__global__ void k_x1(const float* __restrict__ h, const float* __restrict__ w,
                     float* __restrict__ x1) {
  __shared__ float hs[4][HID];
  int i0 = blockIdx.x * 4;
  int j = threadIdx.x;
#pragma unroll
  for (int m = 0; m < 4; ++m) hs[m][j] = h[(i0 + m) * HID + j];
  __syncthreads();
  float a0 = 0.f, a1 = 0.f, a2 = 0.f, a3 = 0.f;
  for (int k = 0; k < HID; ++k) {
    float wv = w[k * NF + j];
    a0 = fmaf(hs[0][k], wv, a0);
    a1 = fmaf(hs[1][k], wv, a1);
    a2 = fmaf(hs[2][k], wv, a2);
    a3 = fmaf(hs[3][k], wv, a3);
  }
  x1[(i0 + 0) * NF + j] = a0;
  x1[(i0 + 1) * NF + j] = a1;
  x1[(i0 + 2) * NF + j] = a2;
  x1[(i0 + 3) * NF + j] = a3;
}

// ---------------- per-molecule edge kernel: LDS staging + LDS atomics ----------------
__global__ void __launch_bounds__(256) k_edge_mol(
    const float* __restrict__ dist, const int* __restrict__ ei,
    const float* __restrict__ table, const float* __restrict__ x1,
    float* __restrict__ agg) {
  __shared__ float sx1[NPG * NF];   // 20 KB
  __shared__ float sagg[NPG * NF];  // 20 KB
  int g = blockIdx.x;
  int a0 = g * NPG;
  int t = threadIdx.x;
  // stage x1 (float4 coalesced) and zero sagg
  const float4* xin = (const float4*)(x1 + (size_t)a0 * NF);
  float4* sx4 = (float4*)sx1;
  float4* sa4 = (float4*)sagg;
  const float4 z4 = make_float4(0.f, 0.f, 0.f, 0.f);
#pragma unroll
  for (int i = 0; i < (NPG * NF / 4) / 256; ++i) {
    sx4[t + i * 256] = xin[t + i * 256];
    sa4[t + i * 256] = z4;
  }
  __syncthreads();

  int wave = t >> 6, lane = t & 63;
  int ebase = a0 * DEG;
  const float tscale = (float)(TBL - 1) / CUTOFF;
  for (int eo = wave; eo < EPM; eo += 4) {
    int e = ebase + eo;
    float d = dist[e];
    int row = ei[e] - a0;
    int col = ei[E_EDGES + e] - a0;
    float ft = d * tscale;
    int i0 = (int)ft;
    i0 = min(i0, TBL - 2);
    float fr = ft - (float)i0;
    float2 ta = ((const float2*)(table + (size_t)i0 * NF))[lane];
    float2 tb = ((const float2*)(table + (size_t)(i0 + 1) * NF))[lane];
    float w0 = fmaf(fr, tb.x - ta.x, ta.x);
    float w1 = fmaf(fr, tb.y - ta.y, ta.y);
    float2 xv = ((const float2*)(sx1 + row * NF))[lane];
    atomicAdd(&sagg[col * NF + 2 * lane + 0], xv.x * w0);
    atomicAdd(&sagg[col * NF + 2 * lane + 1], xv.y * w1);
  }
  __syncthreads();
  float4* aout = (float4*)(agg + (size_t)a0 * NF);
#pragma unroll
  for (int i = 0; i < (NPG * NF / 4) / 256; ++i) aout[t + i * 256] = sa4[t + i * 256];
}

// ---------------- node update: h += (ssp(agg@cf_w2+b2)) @ lin_w + lin_b ----------------
__global__ void k_update(const float* __restrict__ agg, const float* __restrict__ w2,
                         const float* __restrict__ b2, const float* __restrict__ lw,
                         const float* __restrict__ lb, float* __restrict__ h) {
  __shared__ float s[4][NF];
  __shared__ float u[4][NF];
  int i0 = blockIdx.x * 4;
  int j = threadIdx.x;
#pragma unroll
  for (int m = 0; m < 4; ++m) s[m][j] = agg[(i0 + m) * NF + j];
  __syncthreads();
  float bj = b2[j];
  float a0 = bj, a1 = bj, a2 = bj, a3 = bj;
  for (int k = 0; k < NF; ++k) {
    float wv = w2[k * HID + j];
    a0 = fmaf(s[0][k], wv, a0);
    a1 = fmaf(s[1][k], wv, a1);
    a2 = fmaf(s[2][k], wv, a2);
    a3 = fmaf(s[3][k], wv, a3);
  }
  u[0][j] = ssp_f(a0);
  u[1][j] = ssp_f(a1);
  u[2][j] = ssp_f(a2);
  u[3][j] = ssp_f(a3);
  __syncthreads();
  float lbj = lb[j];
  a0 = lbj; a1 = lbj; a2 = lbj; a3 = lbj;
  for (int k = 0; k < HID; ++k) {
    float wv = lw[k * HID + j];
    a0 = fmaf(u[0][k], wv, a0);
    a1 = fmaf(u[1][k], wv, a1);
    a2 = fmaf(u[2][k], wv, a2);
    a3 = fmaf(u[3][k], wv, a3);
  }
  h[(i0 + 0) * HID + j] += a0;
  h[(i0 + 1) * HID + j] += a1;
  h[(i0 + 2) * HID + j] += a2;
  h[(i0 + 3) * HID + j] += a3;
}

// ---------------- head ----------------
__global__ void k_head(const float* __restrict__ h, const float* __restrict__ hw1,
                       const float* __restrict__ hb1, const float* __restrict__ hw2,
                       const float* __restrict__ hb2, const int* __restrict__ batch,
                       float* __restrict__ out) {
  __shared__ float hs[4][HID];
  int i0 = blockIdx.x * 4;
  int j = threadIdx.x;  // 0..63
  for (int idx = j; idx < 4 * HID; idx += 64) hs[idx >> 7][idx & 127] = h[i0 * HID + idx];
  __syncthreads();
  float bj = hb1[j];
  float acc[4];
#pragma unroll
  for (int m = 0; m < 4; ++m) acc[m] = bj;
  for (int k = 0; k < HID; ++k) {
    float wv = hw1[k * 64 + j];
#pragma unroll
    for (int m = 0; m < 4; ++m) acc[m] = fmaf(hs[m][k], wv, acc[m]);
  }
  float w2v = hw2[j];
  float b2v = hb2[0];
  float ysum = 0.f;
#pragma unroll
  for (int m = 0; m < 4; ++m) {
    float p = ssp_f(acc[m]) * w2v;
    for (int off = 32; off > 0; off >>= 1) p += __shfl_down(p, off);
    if (j == 0) ysum += p + b2v;
  }
  if (j == 0) atomicAdd(&out[batch[i0]], ysum);
}

extern "C" void kernel_launch(void* const* d_in, const int* in_sizes, int n_in,
                              void* d_out, int out_size, void* d_ws, size_t ws_size,
                              hipStream_t stream) {
  const float* pos    = (const float*)d_in[0];
  const float* emb    = (const float*)d_in[1];
  const float* mlp_w1 = (const float*)d_in[2];
  const float* mlp_b1 = (const float*)d_in[3];
  const float* mlp_w2 = (const float*)d_in[4];
  const float* mlp_b2 = (const float*)d_in[5];
  const float* cf_w1  = (const float*)d_in[6];
  const float* cf_w2  = (const float*)d_in[7];
  const float* cf_b2  = (const float*)d_in[8];
  const float* lin_w  = (const float*)d_in[9];
  const float* lin_b  = (const float*)d_in[10];
  const float* hw1    = (const float*)d_in[11];
  const float* hb1    = (const float*)d_in[12];
  const float* hw2    = (const float*)d_in[13];
  const float* hb2    = (const float*)d_in[14];
  const int*   z      = (const int*)d_in[15];
  const int*   batch  = (const int*)d_in[16];
  const int*   ei     = (const int*)d_in[17];

  float* ws  = (float*)d_ws;
  float* dist = ws;                          // E
  float* h    = dist + E_EDGES;              // N*HID
  float* x1   = h + (size_t)N_ATOMS * HID;   // N*NF
  float* agg  = x1 + (size_t)N_ATOMS * NF;   // N*NF
  float* tbl  = agg + (size_t)N_ATOMS * NF;  // 3*TBL*NF
  size_t need = ((size_t)E_EDGES + 3ull * N_ATOMS * HID + 3ull * TBL * NF) * 4ull;
  if (ws_size < need) return;

  k_dist<<<(E_EDGES + 255) / 256, 256, 0, stream>>>(pos, ei, dist);
  k_embed<<<(N_ATOMS * HID + 255) / 256, 256, 0, stream>>>(emb, z, h);
  for (int l = 0; l < 3; ++l) {
    k_table<<<TBL / 16, NF, 0, stream>>>(mlp_w1 + (size_t)l * NF * NF, mlp_b1 + (size_t)l * NF,
                                         mlp_w2 + (size_t)l * NF * NF, mlp_b2 + (size_t)l * NF,
                                         tbl + (size_t)l * TBL * NF);
  }
  for (int l = 0; l < 3; ++l) {
    k_x1<<<N_ATOMS / 4, 128, 0, stream>>>(h, cf_w1 + (size_t)l * HID * NF, x1);
    k_edge_mol<<<G_GRAPHS, 256, 0, stream>>>(dist, ei, tbl + (size_t)l * TBL * NF, x1, agg);
    k_update<<<N_ATOMS / 4, 128, 0, stream>>>(agg, cf_w2 + (size_t)l * NF * HID,
                                              cf_b2 + (size_t)l * HID,
                                              lin_w + (size_t)l * HID * HID,
                                              lin_b + (size_t)l * HID, h);
  }
  hipMemsetAsync(d_out, 0, G_GRAPHS * 4, stream);
  k_head<<<N_ATOMS / 4, 64, 0, stream>>>(h, hw1, hb1, hw2, hb2, batch, (float*)d_out);
}

// Round 3
// 920.485 us; speedup vs baseline: 1.2089x; 1.0214x over previous
//
#include <hip/hip_runtime.h>
#include <math.h>

#define N_ATOMS 20000
#define G_GRAPHS 500
#define NPG 40
#define DEG 16
#define E_EDGES (N_ATOMS * DEG)
#define EPM (NPG * DEG)          // 640 edges per molecule
#define HID 128
#define NF 128
#define TBL 8192
#define CUTOFF 10.0f
#define LOG2F_ 0.6931471805599453f
#define ETHR 512

__device__ __forceinline__ float ssp_f(float x) {
  float ax = fabsf(x);
  return fmaxf(x, 0.0f) + log1pf(expf(-ax)) - LOG2F_;
}

// ---------------- distances -> pre-scaled table coordinate ----------------
__global__ void k_dist(const float* __restrict__ pos, const int* __restrict__ ei,
                       float* __restrict__ ftb) {
  int e = blockIdx.x * blockDim.x + threadIdx.x;
  if (e >= E_EDGES) return;
  int r = ei[e], c = ei[E_EDGES + e];
  float dx = pos[3 * r + 0] - pos[3 * c + 0];
  float dy = pos[3 * r + 1] - pos[3 * c + 1];
  float dz = pos[3 * r + 2] - pos[3 * c + 2];
  ftb[e] = sqrtf(dx * dx + dy * dy + dz * dz) * ((float)(TBL - 1) / CUTOFF);
}

// ---------------- embedding gather ----------------
__global__ void k_embed(const float* __restrict__ emb, const int* __restrict__ z,
                        float* __restrict__ h) {
  int t = blockIdx.x * blockDim.x + threadIdx.x;
  if (t >= N_ATOMS * HID) return;
  int i = t >> 7, c = t & 127;
  h[t] = emb[z[i] * HID + c];
}

// ---------------- filter tables, all 3 layers, 16 rows per block ----------------
__global__ void k_table(const float* __restrict__ w1_, const float* __restrict__ b1_,
                        const float* __restrict__ w2_, const float* __restrict__ b2_,
                        float* __restrict__ table_) {
  __shared__ float ea[16][NF];
  __shared__ float hidv[16][NF];
  int l = blockIdx.y;
  const float* w1 = w1_ + (size_t)l * NF * NF;
  const float* b1 = b1_ + (size_t)l * NF;
  const float* w2 = w2_ + (size_t)l * NF * NF;
  const float* b2 = b2_ + (size_t)l * NF;
  float* table = table_ + (size_t)l * TBL * NF;
  int j = threadIdx.x;
  int rbase = blockIdx.x * 16;
  const float step = CUTOFF / (float)(TBL - 1);
  const float delta = CUTOFF / (float)(NF - 1);
  const float coeff = -0.5f / (delta * delta);
#pragma unroll
  for (int rr = 0; rr < 16; ++rr) {
    float d = step * (float)(rbase + rr);
    float t = d - delta * (float)j;
    ea[rr][j] = expf(coeff * t * t);
  }
  __syncthreads();
  float b1j = b1[j];
  float acc[16];
#pragma unroll
  for (int rr = 0; rr < 16; ++rr) acc[rr] = b1j;
  for (int k = 0; k < NF; ++k) {
    float wv = w1[k * NF + j];
#pragma unroll
    for (int rr = 0; rr < 16; ++rr) acc[rr] = fmaf(ea[rr][k], wv, acc[rr]);
  }
#pragma unroll
  for (int rr = 0; rr < 16; ++rr) hidv[rr][j] = ssp_f(acc[rr]);
  __syncthreads();
  float b2j = b2[j];
#pragma unroll
  for (int rr = 0; rr < 16; ++rr) acc[rr] = b2j;
  for (int k = 0; k < NF; ++k) {
    float wv = w2[k * NF + j];
#pragma unroll
    for (int rr = 0; rr < 16; ++rr) acc[rr] = fmaf(hidv[rr][k], wv, acc[rr]);
  }
#pragma unroll
  for (int rr = 0; rr < 16; ++rr) {
    float d = step * (float)(rbase + rr);
    float C = 0.5f * (cosf(d * (float)M_PI / CUTOFF) + 1.0f);
    table[(size_t)(rbase + rr) * NF + j] = acc[rr] * C;
  }
}

// ---------------- x1 = h @ cf_w1 (8 nodes per block) ----------------
__global__ void k_x1(const float* __restrict__ h, const float* __restrict__ w,
                     float* __restrict__ x1) {
  __shared__ float hs[8][HID];
  int i0 = blockIdx.x * 8;
  int j = threadIdx.x;
#pragma unroll
  for (int m = 0; m < 8; ++m) hs[m][j] = h[(size_t)(i0 + m) * HID + j];
  __syncthreads();
  float acc[8] = {0.f, 0.f, 0.f, 0.f, 0.f, 0.f, 0.f, 0.f};
  for (int k = 0; k < HID; ++k) {
    float wv = w[k * NF + j];
#pragma unroll
    for (int m = 0; m < 8; ++m) acc[m] = fmaf(hs[m][k], wv, acc[m]);
  }
#pragma unroll
  for (int m = 0; m < 8; ++m) x1[(size_t)(i0 + m) * NF + j] = acc[m];
}

// ---------------- per-molecule edge kernel: 8 waves, 4x unroll ----------------
__global__ void __launch_bounds__(ETHR) k_edge_mol(
    const float* __restrict__ ftb, const int* __restrict__ ei,
    const float* __restrict__ table, const float* __restrict__ x1,
    float* __restrict__ agg) {
  __shared__ float sx1[NPG * NF];   // 20 KB
  __shared__ float sagg[NPG * NF];  // 20 KB
  __shared__ float sft[EPM];        // 2.5 KB
  __shared__ int srow[EPM];         // 2.5 KB
  __shared__ int scol[EPM];         // 2.5 KB
  int g = blockIdx.x;
  int a0 = g * NPG;
  int t = threadIdx.x;
  const float4* xin = (const float4*)(x1 + (size_t)a0 * NF);
  float4* sx4 = (float4*)sx1;
  float4* sa4 = (float4*)sagg;
  const float4 z4 = make_float4(0.f, 0.f, 0.f, 0.f);
  for (int i = t; i < NPG * NF / 4; i += ETHR) {
    sx4[i] = xin[i];
    sa4[i] = z4;
  }
  int ebase = a0 * DEG;
  for (int i = t; i < EPM; i += ETHR) {
    sft[i] = ftb[ebase + i];
    srow[i] = ei[ebase + i] - a0;
    scol[i] = ei[E_EDGES + ebase + i] - a0;
  }
  __syncthreads();

  int wave = t >> 6, lane = t & 63;
  for (int eo0 = wave * 4; eo0 < EPM; eo0 += 8 * 4) {
    float2 ta[4], tb[4];
    float fr[4];
    int row[4], col[4];
#pragma unroll
    for (int u = 0; u < 4; ++u) {
      int eo = eo0 + u;
      float ft = sft[eo];
      int i0 = min((int)ft, TBL - 2);
      fr[u] = ft - (float)i0;
      row[u] = srow[eo];
      col[u] = scol[eo];
      ta[u] = ((const float2*)(table + (size_t)i0 * NF))[lane];
      tb[u] = ((const float2*)(table + (size_t)(i0 + 1) * NF))[lane];
    }
#pragma unroll
    for (int u = 0; u < 4; ++u) {
      float w0 = fmaf(fr[u], tb[u].x - ta[u].x, ta[u].x);
      float w1 = fmaf(fr[u], tb[u].y - ta[u].y, ta[u].y);
      float2 xv = ((const float2*)(sx1 + row[u] * NF))[lane];
      atomicAdd(&sagg[col[u] * NF + 2 * lane + 0], xv.x * w0);
      atomicAdd(&sagg[col[u] * NF + 2 * lane + 1], xv.y * w1);
    }
  }
  __syncthreads();
  float4* aout = (float4*)(agg + (size_t)a0 * NF);
  for (int i = t; i < NPG * NF / 4; i += ETHR) aout[i] = sa4[i];
}

// ---------------- node update: h += (ssp(agg@cf_w2+b2)) @ lin_w + lin_b (8 nodes) ----------------
__global__ void k_update(const float* __restrict__ agg, const float* __restrict__ w2,
                         const float* __restrict__ b2, const float* __restrict__ lw,
                         const float* __restrict__ lb, float* __restrict__ h) {
  __shared__ float s[8][NF];
  __shared__ float u[8][NF];
  int i0 = blockIdx.x * 8;
  int j = threadIdx.x;
#pragma unroll
  for (int m = 0; m < 8; ++m) s[m][j] = agg[(size_t)(i0 + m) * NF + j];
  __syncthreads();
  float bj = b2[j];
  float acc[8];
#pragma unroll
  for (int m = 0; m < 8; ++m) acc[m] = bj;
  for (int k = 0; k < NF; ++k) {
    float wv = w2[k * HID + j];
#pragma unroll
    for (int m = 0; m < 8; ++m) acc[m] = fmaf(s[m][k], wv, acc[m]);
  }
#pragma unroll
  for (int m = 0; m < 8; ++m) u[m][j] = ssp_f(acc[m]);
  __syncthreads();
  float lbj = lb[j];
#pragma unroll
  for (int m = 0; m < 8; ++m) acc[m] = lbj;
  for (int k = 0; k < HID; ++k) {
    float wv = lw[k * HID + j];
#pragma unroll
    for (int m = 0; m < 8; ++m) acc[m] = fmaf(u[m][k], wv, acc[m]);
  }
#pragma unroll
  for (int m = 0; m < 8; ++m) h[(size_t)(i0 + m) * HID + j] += acc[m];
}

// ---------------- head ----------------
__global__ void k_head(const float* __restrict__ h, const float* __restrict__ hw1,
                       const float* __restrict__ hb1, const float* __restrict__ hw2,
                       const float* __restrict__ hb2, const int* __restrict__ batch,
                       float* __restrict__ out) {
  __shared__ float hs[4][HID];
  int i0 = blockIdx.x * 4;
  int j = threadIdx.x;  // 0..63
  for (int idx = j; idx < 4 * HID; idx += 64) hs[idx >> 7][idx & 127] = h[(size_t)i0 * HID + idx];
  __syncthreads();
  float bj = hb1[j];
  float acc[4];
#pragma unroll
  for (int m = 0; m < 4; ++m) acc[m] = bj;
  for (int k = 0; k < HID; ++k) {
    float wv = hw1[k * 64 + j];
#pragma unroll
    for (int m = 0; m < 4; ++m) acc[m] = fmaf(hs[m][k], wv, acc[m]);
  }
  float w2v = hw2[j];
  float b2v = hb2[0];
  float ysum = 0.f;
#pragma unroll
  for (int m = 0; m < 4; ++m) {
    float p = ssp_f(acc[m]) * w2v;
    for (int off = 32; off > 0; off >>= 1) p += __shfl_down(p, off);
    if (j == 0) ysum += p + b2v;
  }
  if (j == 0) atomicAdd(&out[batch[i0]], ysum);
}

extern "C" void kernel_launch(void* const* d_in, const int* in_sizes, int n_in,
                              void* d_out, int out_size, void* d_ws, size_t ws_size,
                              hipStream_t stream) {
  const float* pos    = (const float*)d_in[0];
  const float* emb    = (const float*)d_in[1];
  const float* mlp_w1 = (const float*)d_in[2];
  const float* mlp_b1 = (const float*)d_in[3];
  const float* mlp_w2 = (const float*)d_in[4];
  const float* mlp_b2 = (const float*)d_in[5];
  const float* cf_w1  = (const float*)d_in[6];
  const float* cf_w2  = (const float*)d_in[7];
  const float* cf_b2  = (const float*)d_in[8];
  const float* lin_w  = (const float*)d_in[9];
  const float* lin_b  = (const float*)d_in[10];
  const float* hw1    = (const float*)d_in[11];
  const float* hb1    = (const float*)d_in[12];
  const float* hw2    = (const float*)d_in[13];
  const float* hb2    = (const float*)d_in[14];
  const int*   z      = (const int*)d_in[15];
  const int*   batch  = (const int*)d_in[16];
  const int*   ei     = (const int*)d_in[17];

  float* ws  = (float*)d_ws;
  float* ftb  = ws;                          // E
  float* h    = ftb + E_EDGES;               // N*HID
  float* x1   = h + (size_t)N_ATOMS * HID;   // N*NF
  float* agg  = x1 + (size_t)N_ATOMS * NF;   // N*NF
  float* tbl  = agg + (size_t)N_ATOMS * NF;  // 3*TBL*NF
  size_t need = ((size_t)E_EDGES + 3ull * N_ATOMS * HID + 3ull * TBL * NF) * 4ull;
  if (ws_size < need) return;

  k_dist<<<(E_EDGES + 255) / 256, 256, 0, stream>>>(pos, ei, ftb);
  k_embed<<<(N_ATOMS * HID + 255) / 256, 256, 0, stream>>>(emb, z, h);
  k_table<<<dim3(TBL / 16, 3), NF, 0, stream>>>(mlp_w1, mlp_b1, mlp_w2, mlp_b2, tbl);
  for (int l = 0; l < 3; ++l) {
    k_x1<<<N_ATOMS / 8, 128, 0, stream>>>(h, cf_w1 + (size_t)l * HID * NF, x1);
    k_edge_mol<<<G_GRAPHS, ETHR, 0, stream>>>(ftb, ei, tbl + (size_t)l * TBL * NF, x1, agg);
    k_update<<<N_ATOMS / 8, 128, 0, stream>>>(agg, cf_w2 + (size_t)l * NF * HID,
                                              cf_b2 + (size_t)l * HID,
                                              lin_w + (size_t)l * HID * HID,
                                              lin_b + (size_t)l * HID, h);
  }
  hipMemsetAsync(d_out, 0, G_GRAPHS * 4, stream);
  k_head<<<N_ATOMS / 4, 64, 0, stream>>>(h, hw1, hb1, hw2, hb2, batch, (float*)d_out);
}